// Round 9
// baseline (645.352 us; speedup 1.0000x reference)
//
#include <hip/hip_runtime.h>

#define B_ 8
#define S_ 1024
#define E_ 1024
#define H_ 16
#define D_ 64

typedef __attribute__((ext_vector_type(8))) __bf16 bf16x8;
typedef __attribute__((ext_vector_type(4))) float f32x4;
typedef __attribute__((ext_vector_type(4))) unsigned short u16x4;
typedef __attribute__((ext_vector_type(8))) unsigned short u16x8;

static __device__ __forceinline__ unsigned short f2bf_hw(float f) {
  union { __bf16 b; unsigned short u; } v;
  v.b = (__bf16)f;
  return v.u;
}

#if __has_builtin(__builtin_amdgcn_exp2f)
#define EXP2(x) __builtin_amdgcn_exp2f(x)
#else
#define EXP2(x) exp2f(x)
#endif
#define SCALE2 0.18033688f  /* 0.125 * log2(e) */

#define MFMA16(a, b, c) __builtin_amdgcn_mfma_f32_16x16x32_bf16((a), (b), (c), 0, 0, 0)

// ---------------- cast h (fp32 -> bf16), vectorized ----------------
__global__ void cast_f32_bf16_kernel(const float* __restrict__ src,
                                     unsigned short* __restrict__ dst, int n4) {
  int i = blockIdx.x * 256 + threadIdx.x;
  if (i >= n4) return;
  float4 v = reinterpret_cast<const float4*>(src)[i];
  u16x4 o;
  o[0] = f2bf_hw(v.x); o[1] = f2bf_hw(v.y); o[2] = f2bf_hw(v.z); o[3] = f2bf_hw(v.w);
  reinterpret_cast<u16x4*>(dst)[i] = o;
}

// ---------------- transpose + cast: dst[c][r] = bf16(src[r][c]) ----------------
__global__ void transpose_cast_kernel(const float* __restrict__ src,
                                      unsigned short* __restrict__ dst,
                                      int rows, int cols) {
  __shared__ unsigned short tile[64][65];
  const float* s = src + (size_t)blockIdx.z * rows * cols;
  unsigned short* d = dst + (size_t)blockIdx.z * rows * cols;
  int rb = blockIdx.y * 64, cb = blockIdx.x * 64;
#pragma unroll
  for (int k = 0; k < 16; k++) {
    int idx = threadIdx.x + 256 * k;
    int r = idx >> 6, c = idx & 63;
    tile[r][c] = f2bf_hw(s[(size_t)(rb + r) * cols + cb + c]);
  }
  __syncthreads();
#pragma unroll
  for (int k = 0; k < 16; k++) {
    int idx = threadIdx.x + 256 * k;
    int r = idx >> 6, c = idx & 63;
    d[(size_t)(cb + r) * rows + rb + c] = tile[c][r];
  }
}

// ---------------- G^T tiled: Gt[b][e/256][t/32][e%256][t%32] = (h@Wo)^T ----------------
__launch_bounds__(256)
__global__ void gemm_G_kernel(const unsigned short* __restrict__ hb,
                              const unsigned short* __restrict__ WoT,
                              unsigned short* __restrict__ Gt) {
  int mblk = blockIdx.x, nblk = blockIdx.y, b = blockIdx.z;
  const unsigned short* A = hb + (size_t)b * S_ * E_;
  int tid = threadIdx.x, l = tid & 63, w = tid >> 6;
  int ws = w & 1, wc = w >> 1, lr = l & 15, lg = l >> 4;
  f32x4 acc[4][4] = {};
  int ar[4], bc[4];
#pragma unroll
  for (int i = 0; i < 4; i++) ar[i] = mblk * 128 + ws * 64 + i * 16 + lr;
#pragma unroll
  for (int j = 0; j < 4; j++) bc[j] = nblk * 128 + wc * 64 + j * 16 + lr;
  for (int k0 = 0; k0 < E_; k0 += 32) {
    bf16x8 a[4], bb[4];
#pragma unroll
    for (int i = 0; i < 4; i++)
      a[i] = *reinterpret_cast<const bf16x8*>(A + (size_t)ar[i] * E_ + k0 + lg * 8);
#pragma unroll
    for (int j = 0; j < 4; j++)
      bb[j] = *reinterpret_cast<const bf16x8*>(WoT + (size_t)bc[j] * E_ + k0 + lg * 8);
#pragma unroll
    for (int i = 0; i < 4; i++)
#pragma unroll
      for (int j = 0; j < 4; j++)
        acc[i][j] = MFMA16(a[i], bb[j], acc[i][j]);
  }
#pragma unroll
  for (int i = 0; i < 4; i++) {
    int t0 = mblk * 128 + ws * 64 + i * 16 + lg * 4;
#pragma unroll
    for (int j = 0; j < 4; j++) {
      u16x4 p;
#pragma unroll
      for (int r = 0; r < 4; r++) p[r] = f2bf_hw(acc[i][j][r]);
      int e = bc[j];
      size_t addr = (((size_t)b * 4 + (e >> 8)) * 32 + (t0 >> 5)) * 8192 +
                    (size_t)(e & 255) * 32 + (t0 & 31);
      *reinterpret_cast<u16x4*>(Gt + addr) = p;
    }
  }
}

// ---------------- fused Q&K projection ----------------
__launch_bounds__(256)
__global__ void proj_qk_kernel(const unsigned short* __restrict__ hb,
                               const unsigned short* __restrict__ WqT,
                               const unsigned short* __restrict__ WkT,
                               const float* __restrict__ bq,
                               const float* __restrict__ bk,
                               unsigned short* __restrict__ Qb,
                               unsigned short* __restrict__ Kb) {
  int sblk = blockIdx.x, z = blockIdx.y;
  int b = z >> 4, h = z & 15;
  const unsigned short* A = hb + (size_t)b * S_ * E_;
  const unsigned short* Btq = WqT + (size_t)h * D_ * E_;
  const unsigned short* Btk = WkT + (size_t)h * D_ * E_;
  int tid = threadIdx.x, l = tid & 63, w = tid >> 6;
  int ws = w & 1, wc = w >> 1, lr = l & 15, lg = l >> 4;
  f32x4 accq[4][2] = {}, acck[4][2] = {};
  int ar[4], bc[2];
#pragma unroll
  for (int i = 0; i < 4; i++) ar[i] = sblk * 128 + ws * 64 + i * 16 + lr;
#pragma unroll
  for (int j = 0; j < 2; j++) bc[j] = wc * 32 + j * 16 + lr;
  for (int k0 = 0; k0 < E_; k0 += 32) {
    bf16x8 a[4], bbq[2], bbk[2];
#pragma unroll
    for (int i = 0; i < 4; i++)
      a[i] = *reinterpret_cast<const bf16x8*>(A + (size_t)ar[i] * E_ + k0 + lg * 8);
#pragma unroll
    for (int j = 0; j < 2; j++) {
      bbq[j] = *reinterpret_cast<const bf16x8*>(Btq + (size_t)bc[j] * E_ + k0 + lg * 8);
      bbk[j] = *reinterpret_cast<const bf16x8*>(Btk + (size_t)bc[j] * E_ + k0 + lg * 8);
    }
#pragma unroll
    for (int i = 0; i < 4; i++)
#pragma unroll
      for (int j = 0; j < 2; j++) {
        accq[i][j] = MFMA16(a[i], bbq[j], accq[i][j]);
        acck[i][j] = MFMA16(a[i], bbk[j], acck[i][j]);
      }
  }
  unsigned short* oq = Qb + (size_t)z * S_ * D_;
  unsigned short* ok = Kb + (size_t)z * S_ * D_;
#pragma unroll
  for (int j = 0; j < 2; j++) {
    float bvq = bq[h * D_ + bc[j]], bvk = bk[h * D_ + bc[j]];
#pragma unroll
    for (int i = 0; i < 4; i++)
#pragma unroll
      for (int r = 0; r < 4; r++) {
        int s = sblk * 128 + ws * 64 + i * 16 + lg * 4 + r;
        oq[(size_t)s * D_ + bc[j]] = f2bf_hw(accq[i][j][r] + bvq);
        ok[(size_t)s * D_ + bc[j]] = f2bf_hw(acck[i][j][r] + bvk);
      }
  }
}

// ---------------- column logsumexp stats (scaled by log2e): cL[z][t] ----------------
__launch_bounds__(256)
__global__ void stats_kernel(const unsigned short* __restrict__ Qb,
                             const unsigned short* __restrict__ Kb,
                             float* __restrict__ c) {
  int tblk = blockIdx.x, z = blockIdx.y;
  const unsigned short* Q = Qb + (size_t)z * S_ * D_;
  const unsigned short* K = Kb + (size_t)z * S_ * D_;
  int tid = threadIdx.x, l = tid & 63, w = tid >> 6;
  int lr = l & 15, lg = l >> 4;
  int tb = tblk * 256 + w * 64;
  const float scale = 0.125f;
  bf16x8 kb[4][2];
#pragma unroll
  for (int j = 0; j < 4; j++)
#pragma unroll
    for (int ks = 0; ks < 2; ks++)
      kb[j][ks] = *reinterpret_cast<const bf16x8*>(
          K + (size_t)(tb + j * 16 + lr) * D_ + ks * 32 + lg * 8);
  float m[4], zz[4];
#pragma unroll
  for (int j = 0; j < 4; j++) { m[j] = -1e30f; zz[j] = 0.f; }
  for (int s0 = 0; s0 < S_; s0 += 32) {
    bf16x8 aq[2][2];
#pragma unroll
    for (int sf = 0; sf < 2; sf++)
#pragma unroll
      for (int ks = 0; ks < 2; ks++)
        aq[sf][ks] = *reinterpret_cast<const bf16x8*>(
            Q + (size_t)(s0 + sf * 16 + lr) * D_ + ks * 32 + lg * 8);
    f32x4 acc[2][4] = {};
#pragma unroll
    for (int sf = 0; sf < 2; sf++)
#pragma unroll
      for (int j = 0; j < 4; j++) {
        acc[sf][j] = MFMA16(aq[sf][0], kb[j][0], acc[sf][j]);
        acc[sf][j] = MFMA16(aq[sf][1], kb[j][1], acc[sf][j]);
      }
#pragma unroll
    for (int j = 0; j < 4; j++) {
      float v[8];
#pragma unroll
      for (int sf = 0; sf < 2; sf++)
#pragma unroll
        for (int r = 0; r < 4; r++) v[sf * 4 + r] = acc[sf][j][r] * scale;
      float mx = m[j];
#pragma unroll
      for (int t = 0; t < 8; t++) mx = fmaxf(mx, v[t]);
      float sum = 0.f;
#pragma unroll
      for (int t = 0; t < 8; t++) sum += __expf(v[t] - mx);
      zz[j] = zz[j] * __expf(m[j] - mx) + sum;
      m[j] = mx;
    }
  }
#pragma unroll
  for (int j = 0; j < 4; j++) {
    float mj = m[j], zj = zz[j];
#pragma unroll
    for (int off = 16; off <= 32; off <<= 1) {
      float om = __shfl_xor(mj, off, 64);
      float oz = __shfl_xor(zj, off, 64);
      float mn = fmaxf(mj, om);
      zj = zj * __expf(mj - mn) + oz * __expf(om - mn);
      mj = mn;
    }
    if (l < 16)
      c[(size_t)z * S_ + tb + j * 16 + lr] = (mj + __logf(zj)) * 1.44269504f;
  }
}

// ---------------- fused attention + output projection ----------------
// R8 structure + software pipeline: PV lags one window. Per window:
//   stage K(IT+1); kreg=K(IT+2); QK(IT) from Ks[cur] -> exp2 -> Ps[cur];
//   PV(IT-1) from Ps[prev] x G-regs(IT-1); issue G(IT+1) into same regs;
//   ONE __syncthreads().
// G(j) lives in vA if j even, vB if j odd (consumed at window j+1, reissued there).
__launch_bounds__(256, 3)
__global__ void attn_kernel(const unsigned short* __restrict__ Qb,
                            const unsigned short* __restrict__ Kb,
                            const unsigned short* __restrict__ Gt,
                            const float* __restrict__ cst,   // c * log2(e)
                            const float* __restrict__ bo,
                            float* __restrict__ out) {
  int n = blockIdx.x;
  int b = n & 7, h = (n >> 3) & 15, eblk = (n >> 7) & 3, sblk = n >> 9;
  int z = b * 16 + h;
  __shared__ unsigned short Ks[2][32][72];
  __shared__ unsigned short Ps[2][64][40];
  int tid = threadIdx.x, l = tid & 63, w = tid >> 6;
  int lr = l & 15, lg = l >> 4;
  const unsigned short* Q = Qb + (size_t)z * S_ * D_ + (size_t)(sblk * 64) * D_;
  const unsigned short* K = Kb + (size_t)z * S_ * D_;
  const unsigned short* Gb = Gt + (((size_t)b * 4 + eblk) * 32) * 8192;
  const float* cz = cst + (size_t)z * S_;

  // Q fragments: wave w handles QK for s-rows [w*16, w*16+16)
  bf16x8 q[2];
#pragma unroll
  for (int ks = 0; ks < 2; ks++)
    q[ks] = *reinterpret_cast<const bf16x8*>(
        Q + (size_t)(w * 16 + lr) * D_ + ks * 32 + lg * 8);

  // per-lane G fragment offset within a 32-t tile (row = w*64 + j*16 + lr)
  size_t goff[4];
#pragma unroll
  for (int j = 0; j < 4; j++)
    goff[j] = (size_t)(w * 64 + j * 16 + lr) * 32 + lg * 8;

  int krow = tid >> 3, kc8 = (tid & 7) * 8;
  u16x8 kreg;
  bf16x8 vA[4], vB[4];

  // prologue: K(0)->Ks[0]; kreg=K(1); vA=G(0)
  kreg = *reinterpret_cast<const u16x8*>(K + (size_t)krow * D_ + kc8);
  *reinterpret_cast<u16x8*>(&Ks[0][krow][kc8]) = kreg;
  kreg = *reinterpret_cast<const u16x8*>(K + (size_t)(32 + krow) * D_ + kc8);
#pragma unroll
  for (int j = 0; j < 4; j++)
    vA[j] = *reinterpret_cast<const bf16x8*>(Gb + goff[j]);
  __syncthreads();

  f32x4 acc[4][4] = {};

#define WINDOW(IT, CUR, VPREV, HASPV)                                             \
  do {                                                                            \
    int t0_ = (IT) * 32;                                                          \
    /* stage K(IT+1) -> Ks[CUR^1]; issue kreg = K(IT+2) */                        \
    *reinterpret_cast<u16x8*>(&Ks[(CUR) ^ 1][krow][kc8]) = kreg;                  \
    {                                                                             \
      int tk_ = ((IT) + 2) & 31;                                                  \
      kreg = *reinterpret_cast<const u16x8*>(                                     \
          K + (size_t)(tk_ * 32 + krow) * D_ + kc8);                              \
    }                                                                             \
    /* QK(IT) from Ks[CUR] */                                                     \
    f32x4 sa_[2] = {};                                                            \
    {                                                                             \
      bf16x8 ka_[2][2];                                                           \
      _Pragma("unroll") for (int tf = 0; tf < 2; tf++)                            \
        _Pragma("unroll") for (int ks = 0; ks < 2; ks++)                          \
          ka_[tf][ks] = *reinterpret_cast<const bf16x8*>(                         \
              &Ks[CUR][tf * 16 + lr][ks * 32 + lg * 8]);                          \
      _Pragma("unroll") for (int tf = 0; tf < 2; tf++) {                          \
        sa_[tf] = MFMA16(ka_[tf][0], q[0], sa_[tf]);                              \
        sa_[tf] = MFMA16(ka_[tf][1], q[1], sa_[tf]);                              \
      }                                                                           \
    }                                                                             \
    /* PV(IT-1): Ps[CUR^1] x VPREV (independent of QK -> overlaps) */             \
    if (HASPV) {                                                                  \
      bf16x8 ap_[4];                                                              \
      _Pragma("unroll") for (int i = 0; i < 4; i++)                               \
        ap_[i] = *reinterpret_cast<const bf16x8*>(                                \
            &Ps[(CUR) ^ 1][i * 16 + lr][lg * 8]);                                 \
      __builtin_amdgcn_s_setprio(1);                                              \
      _Pragma("unroll") for (int i = 0; i < 4; i++)                               \
        _Pragma("unroll") for (int j = 0; j < 4; j++)                             \
          acc[i][j] = MFMA16(ap_[i], VPREV[j], acc[i][j]);                        \
      __builtin_amdgcn_s_setprio(0);                                              \
    }                                                                             \
    /* issue G(IT+1) into VPREV regs (consumed at window IT+2... parity) */       \
    {                                                                             \
      int tg_ = ((IT) + 1) & 31;                                                  \
      _Pragma("unroll") for (int j = 0; j < 4; j++)                               \
        VPREV[j] = *reinterpret_cast<const bf16x8*>(                              \
            Gb + (size_t)tg_ * 8192 + goff[j]);                                   \
    }                                                                             \
    /* exp2(QK) -> Ps[CUR] */                                                     \
    _Pragma("unroll") for (int tf = 0; tf < 2; tf++) {                            \
      f32x4 cv_ = *reinterpret_cast<const f32x4*>(cz + t0_ + tf * 16 + lg * 4);   \
      u16x4 p_;                                                                   \
      _Pragma("unroll") for (int r = 0; r < 4; r++)                               \
        p_[r] = f2bf_hw(EXP2(fmaf(sa_[tf][r], SCALE2, -cv_[r])));                 \
      *reinterpret_cast<u16x4*>(&Ps[CUR][w * 16 + lr][tf * 16 + lg * 4]) = p_;    \
    }                                                                             \
    __syncthreads();                                                              \
  } while (0)

  for (int it2 = 0; it2 < 16; ++it2) {
    WINDOW(it2 * 2, 0, vB, (it2 > 0));
    WINDOW(it2 * 2 + 1, 1, vA, true);
  }
#undef WINDOW

  { // final PV(31): Ps[1] x G(31) (in vB, loaded at window 30)
    bf16x8 ap_[4];
#pragma unroll
    for (int i = 0; i < 4; i++)
      ap_[i] = *reinterpret_cast<const bf16x8*>(&Ps[1][i * 16 + lr][lg * 8]);
#pragma unroll
    for (int i = 0; i < 4; i++)
#pragma unroll
      for (int j = 0; j < 4; j++)
        acc[i][j] = MFMA16(ap_[i], vB[j], acc[i][j]);
  }

  // epilogue: out[b][h*S + s][e] = acc + bo[e]
  float bov[4];
#pragma unroll
  for (int j = 0; j < 4; j++) bov[j] = bo[eblk * 256 + w * 64 + j * 16 + lr];
#pragma unroll
  for (int i = 0; i < 4; i++)
#pragma unroll
    for (int j = 0; j < 4; j++)
#pragma unroll
      for (int r = 0; r < 4; r++) {
        int s = sblk * 64 + i * 16 + lg * 4 + r;
        int col = eblk * 256 + w * 64 + j * 16 + lr;
        out[((size_t)b * (H_ * S_) + (size_t)h * S_ + s) * E_ + col] =
            acc[i][j][r] + bov[j];
      }
}

extern "C" void kernel_launch(void* const* d_in, const int* in_sizes, int n_in,
                              void* d_out, int out_size, void* d_ws, size_t ws_size,
                              hipStream_t stream) {
  const float* h  = (const float*)d_in[0];
  const float* Wq = (const float*)d_in[1];
  const float* bq = (const float*)d_in[2];
  const float* Wk = (const float*)d_in[3];
  const float* bk = (const float*)d_in[4];
  // d_in[5] = Wv, d_in[6] = bv: dead weights in the reference
  const float* Wo = (const float*)d_in[7];
  const float* bo = (const float*)d_in[8];
  float* out = (float*)d_out;

  char* p = (char*)d_ws;
  unsigned short* hb  = (unsigned short*)p; p += (size_t)B_ * S_ * E_ * 2;
  unsigned short* WoT = (unsigned short*)p; p += (size_t)E_ * E_ * 2;
  unsigned short* WqT = (unsigned short*)p; p += (size_t)H_ * D_ * E_ * 2;
  unsigned short* WkT = (unsigned short*)p; p += (size_t)H_ * D_ * E_ * 2;
  unsigned short* Qb  = (unsigned short*)p; p += (size_t)B_ * H_ * S_ * D_ * 2;
  unsigned short* Kb  = (unsigned short*)p; p += (size_t)B_ * H_ * S_ * D_ * 2;
  unsigned short* Gt  = (unsigned short*)p; p += (size_t)B_ * E_ * S_ * 2;
  float*          cst = (float*)p;          p += (size_t)B_ * H_ * S_ * 4;

  int n4 = B_ * S_ * E_ / 4;
  cast_f32_bf16_kernel<<<dim3(n4 / 256), 256, 0, stream>>>(h, hb, n4);
  transpose_cast_kernel<<<dim3(16, 16, 1), 256, 0, stream>>>(Wo, WoT, E_, E_);
  transpose_cast_kernel<<<dim3(1, 16, H_), 256, 0, stream>>>(Wq, WqT, E_, D_);
  transpose_cast_kernel<<<dim3(1, 16, H_), 256, 0, stream>>>(Wk, WkT, E_, D_);
  gemm_G_kernel<<<dim3(8, 8, B_), 256, 0, stream>>>(hb, WoT, Gt);
  proj_qk_kernel<<<dim3(8, B_ * H_), 256, 0, stream>>>(hb, WqT, WkT, bq, bk, Qb, Kb);
  stats_kernel<<<dim3(S_ / 256, B_ * H_), 256, 0, stream>>>(Qb, Kb, cst);
  attn_kernel<<<dim3(8192), 256, 0, stream>>>(Qb, Kb, Gt, cst, bo, out);
}

// Round 10
// 629.176 us; speedup vs baseline: 1.0257x; 1.0257x over previous
//
#include <hip/hip_runtime.h>

#define B_ 8
#define S_ 1024
#define E_ 1024
#define H_ 16
#define D_ 64

typedef __attribute__((ext_vector_type(8))) __bf16 bf16x8;
typedef __attribute__((ext_vector_type(4))) float f32x4;
typedef __attribute__((ext_vector_type(4))) unsigned short u16x4;
typedef __attribute__((ext_vector_type(8))) unsigned short u16x8;

static __device__ __forceinline__ unsigned short f2bf_hw(float f) {
  union { __bf16 b; unsigned short u; } v;
  v.b = (__bf16)f;
  return v.u;
}

#if __has_builtin(__builtin_amdgcn_exp2f)
#define EXP2(x) __builtin_amdgcn_exp2f(x)
#else
#define EXP2(x) exp2f(x)
#endif
#define SCALE2 0.18033688f  /* 0.125 * log2(e) */

#define MFMA16(a, b, c) __builtin_amdgcn_mfma_f32_16x16x32_bf16((a), (b), (c), 0, 0, 0)

// ---------------- cast h (fp32 -> bf16), vectorized ----------------
__global__ void cast_f32_bf16_kernel(const float* __restrict__ src,
                                     unsigned short* __restrict__ dst, int n4) {
  int i = blockIdx.x * 256 + threadIdx.x;
  if (i >= n4) return;
  float4 v = reinterpret_cast<const float4*>(src)[i];
  u16x4 o;
  o[0] = f2bf_hw(v.x); o[1] = f2bf_hw(v.y); o[2] = f2bf_hw(v.z); o[3] = f2bf_hw(v.w);
  reinterpret_cast<u16x4*>(dst)[i] = o;
}

// ---------------- transpose + cast: dst[c][r] = bf16(src[r][c]) ----------------
__global__ void transpose_cast_kernel(const float* __restrict__ src,
                                      unsigned short* __restrict__ dst,
                                      int rows, int cols) {
  __shared__ unsigned short tile[64][65];
  const float* s = src + (size_t)blockIdx.z * rows * cols;
  unsigned short* d = dst + (size_t)blockIdx.z * rows * cols;
  int rb = blockIdx.y * 64, cb = blockIdx.x * 64;
#pragma unroll
  for (int k = 0; k < 16; k++) {
    int idx = threadIdx.x + 256 * k;
    int r = idx >> 6, c = idx & 63;
    tile[r][c] = f2bf_hw(s[(size_t)(rb + r) * cols + cb + c]);
  }
  __syncthreads();
#pragma unroll
  for (int k = 0; k < 16; k++) {
    int idx = threadIdx.x + 256 * k;
    int r = idx >> 6, c = idx & 63;
    d[(size_t)(cb + r) * rows + rb + c] = tile[c][r];
  }
}

// ---------------- G^T tiled: Gt[b][e/256][t/32][e%256][t%32] = (h@Wo)^T ----------------
__launch_bounds__(256)
__global__ void gemm_G_kernel(const unsigned short* __restrict__ hb,
                              const unsigned short* __restrict__ WoT,
                              unsigned short* __restrict__ Gt) {
  int mblk = blockIdx.x, nblk = blockIdx.y, b = blockIdx.z;
  const unsigned short* A = hb + (size_t)b * S_ * E_;
  int tid = threadIdx.x, l = tid & 63, w = tid >> 6;
  int ws = w & 1, wc = w >> 1, lr = l & 15, lg = l >> 4;
  f32x4 acc[4][4] = {};
  int ar[4], bc[4];
#pragma unroll
  for (int i = 0; i < 4; i++) ar[i] = mblk * 128 + ws * 64 + i * 16 + lr;
#pragma unroll
  for (int j = 0; j < 4; j++) bc[j] = nblk * 128 + wc * 64 + j * 16 + lr;
  for (int k0 = 0; k0 < E_; k0 += 32) {
    bf16x8 a[4], bb[4];
#pragma unroll
    for (int i = 0; i < 4; i++)
      a[i] = *reinterpret_cast<const bf16x8*>(A + (size_t)ar[i] * E_ + k0 + lg * 8);
#pragma unroll
    for (int j = 0; j < 4; j++)
      bb[j] = *reinterpret_cast<const bf16x8*>(WoT + (size_t)bc[j] * E_ + k0 + lg * 8);
#pragma unroll
    for (int i = 0; i < 4; i++)
#pragma unroll
      for (int j = 0; j < 4; j++)
        acc[i][j] = MFMA16(a[i], bb[j], acc[i][j]);
  }
#pragma unroll
  for (int i = 0; i < 4; i++) {
    int t0 = mblk * 128 + ws * 64 + i * 16 + lg * 4;
#pragma unroll
    for (int j = 0; j < 4; j++) {
      u16x4 p;
#pragma unroll
      for (int r = 0; r < 4; r++) p[r] = f2bf_hw(acc[i][j][r]);
      int e = bc[j];
      size_t addr = (((size_t)b * 4 + (e >> 8)) * 32 + (t0 >> 5)) * 8192 +
                    (size_t)(e & 255) * 32 + (t0 & 31);
      *reinterpret_cast<u16x4*>(Gt + addr) = p;
    }
  }
}

// ---------------- fused Q&K projection ----------------
__launch_bounds__(256)
__global__ void proj_qk_kernel(const unsigned short* __restrict__ hb,
                               const unsigned short* __restrict__ WqT,
                               const unsigned short* __restrict__ WkT,
                               const float* __restrict__ bq,
                               const float* __restrict__ bk,
                               unsigned short* __restrict__ Qb,
                               unsigned short* __restrict__ Kb) {
  int sblk = blockIdx.x, z = blockIdx.y;
  int b = z >> 4, h = z & 15;
  const unsigned short* A = hb + (size_t)b * S_ * E_;
  const unsigned short* Btq = WqT + (size_t)h * D_ * E_;
  const unsigned short* Btk = WkT + (size_t)h * D_ * E_;
  int tid = threadIdx.x, l = tid & 63, w = tid >> 6;
  int ws = w & 1, wc = w >> 1, lr = l & 15, lg = l >> 4;
  f32x4 accq[4][2] = {}, acck[4][2] = {};
  int ar[4], bc[2];
#pragma unroll
  for (int i = 0; i < 4; i++) ar[i] = sblk * 128 + ws * 64 + i * 16 + lr;
#pragma unroll
  for (int j = 0; j < 2; j++) bc[j] = wc * 32 + j * 16 + lr;
  for (int k0 = 0; k0 < E_; k0 += 32) {
    bf16x8 a[4], bbq[2], bbk[2];
#pragma unroll
    for (int i = 0; i < 4; i++)
      a[i] = *reinterpret_cast<const bf16x8*>(A + (size_t)ar[i] * E_ + k0 + lg * 8);
#pragma unroll
    for (int j = 0; j < 2; j++) {
      bbq[j] = *reinterpret_cast<const bf16x8*>(Btq + (size_t)bc[j] * E_ + k0 + lg * 8);
      bbk[j] = *reinterpret_cast<const bf16x8*>(Btk + (size_t)bc[j] * E_ + k0 + lg * 8);
    }
#pragma unroll
    for (int i = 0; i < 4; i++)
#pragma unroll
      for (int j = 0; j < 2; j++) {
        accq[i][j] = MFMA16(a[i], bbq[j], accq[i][j]);
        acck[i][j] = MFMA16(a[i], bbk[j], acck[i][j]);
      }
  }
  unsigned short* oq = Qb + (size_t)z * S_ * D_;
  unsigned short* ok = Kb + (size_t)z * S_ * D_;
#pragma unroll
  for (int j = 0; j < 2; j++) {
    float bvq = bq[h * D_ + bc[j]], bvk = bk[h * D_ + bc[j]];
#pragma unroll
    for (int i = 0; i < 4; i++)
#pragma unroll
      for (int r = 0; r < 4; r++) {
        int s = sblk * 128 + ws * 64 + i * 16 + lg * 4 + r;
        oq[(size_t)s * D_ + bc[j]] = f2bf_hw(accq[i][j][r] + bvq);
        ok[(size_t)s * D_ + bc[j]] = f2bf_hw(acck[i][j][r] + bvk);
      }
  }
}

// ---------------- column logsumexp stats (scaled by log2e): cL[z][t] ----------------
__launch_bounds__(256)
__global__ void stats_kernel(const unsigned short* __restrict__ Qb,
                             const unsigned short* __restrict__ Kb,
                             float* __restrict__ c) {
  int tblk = blockIdx.x, z = blockIdx.y;
  const unsigned short* Q = Qb + (size_t)z * S_ * D_;
  const unsigned short* K = Kb + (size_t)z * S_ * D_;
  int tid = threadIdx.x, l = tid & 63, w = tid >> 6;
  int lr = l & 15, lg = l >> 4;
  int tb = tblk * 256 + w * 64;
  const float scale = 0.125f;
  bf16x8 kb[4][2];
#pragma unroll
  for (int j = 0; j < 4; j++)
#pragma unroll
    for (int ks = 0; ks < 2; ks++)
      kb[j][ks] = *reinterpret_cast<const bf16x8*>(
          K + (size_t)(tb + j * 16 + lr) * D_ + ks * 32 + lg * 8);
  float m[4], zz[4];
#pragma unroll
  for (int j = 0; j < 4; j++) { m[j] = -1e30f; zz[j] = 0.f; }
  for (int s0 = 0; s0 < S_; s0 += 32) {
    bf16x8 aq[2][2];
#pragma unroll
    for (int sf = 0; sf < 2; sf++)
#pragma unroll
      for (int ks = 0; ks < 2; ks++)
        aq[sf][ks] = *reinterpret_cast<const bf16x8*>(
            Q + (size_t)(s0 + sf * 16 + lr) * D_ + ks * 32 + lg * 8);
    f32x4 acc[2][4] = {};
#pragma unroll
    for (int sf = 0; sf < 2; sf++)
#pragma unroll
      for (int j = 0; j < 4; j++) {
        acc[sf][j] = MFMA16(aq[sf][0], kb[j][0], acc[sf][j]);
        acc[sf][j] = MFMA16(aq[sf][1], kb[j][1], acc[sf][j]);
      }
#pragma unroll
    for (int j = 0; j < 4; j++) {
      float v[8];
#pragma unroll
      for (int sf = 0; sf < 2; sf++)
#pragma unroll
        for (int r = 0; r < 4; r++) v[sf * 4 + r] = acc[sf][j][r] * scale;
      float mx = m[j];
#pragma unroll
      for (int t = 0; t < 8; t++) mx = fmaxf(mx, v[t]);
      float sum = 0.f;
#pragma unroll
      for (int t = 0; t < 8; t++) sum += __expf(v[t] - mx);
      zz[j] = zz[j] * __expf(m[j] - mx) + sum;
      m[j] = mx;
    }
  }
#pragma unroll
  for (int j = 0; j < 4; j++) {
    float mj = m[j], zj = zz[j];
#pragma unroll
    for (int off = 16; off <= 32; off <<= 1) {
      float om = __shfl_xor(mj, off, 64);
      float oz = __shfl_xor(zj, off, 64);
      float mn = fmaxf(mj, om);
      zj = zj * __expf(mj - mn) + oz * __expf(om - mn);
      mj = mn;
    }
    if (l < 16)
      c[(size_t)z * S_ + tb + j * 16 + lr] = (mj + __logf(zj)) * 1.44269504f;
  }
}

// ---------------- fused attention + output projection ----------------
// t-window = 64 (16 windows, ONE barrier each): fixed per-window overhead
// amortized over 2x MFMA. Wave w: QK for its 16 s-rows x 64 t; PV (lagged one
// window) for all 64 s x its 64 e. K dbuf LDS (2-ahead reg prefetch), G
// single-buffered regs v[2][4] (consume-then-reload, full-window cover),
// cst staged to LDS at prologue (broadcast reads, off the exp critical path).
__launch_bounds__(256, 3)
__global__ void attn_kernel(const unsigned short* __restrict__ Qb,
                            const unsigned short* __restrict__ Kb,
                            const unsigned short* __restrict__ Gt,
                            const float* __restrict__ cst,   // c * log2(e)
                            const float* __restrict__ bo,
                            float* __restrict__ out) {
  int n = blockIdx.x;
  int b = n & 7, h = (n >> 3) & 15, eblk = (n >> 7) & 3, sblk = n >> 9;
  int z = b * 16 + h;
  __shared__ unsigned short Ks[2][64][72];
  __shared__ unsigned short Ps[2][64][72];
  __shared__ float csm[1024];
  int tid = threadIdx.x, l = tid & 63, w = tid >> 6;
  int lr = l & 15, lg = l >> 4;
  const unsigned short* Q = Qb + (size_t)z * S_ * D_ + (size_t)(sblk * 64) * D_;
  const unsigned short* K = Kb + (size_t)z * S_ * D_;
  const unsigned short* Gb = Gt + (((size_t)b * 4 + eblk) * 32) * 8192;

  // Q fragments: wave w handles QK for s-rows [w*16, w*16+16)
  bf16x8 q[2];
#pragma unroll
  for (int ks = 0; ks < 2; ks++)
    q[ks] = *reinterpret_cast<const bf16x8*>(
        Q + (size_t)(w * 16 + lr) * D_ + ks * 32 + lg * 8);

  // per-lane G fragment offset within a 32-t Gt tile (row = w*64 + j*16 + lr)
  size_t goff[4];
#pragma unroll
  for (int j = 0; j < 4; j++)
    goff[j] = (size_t)(w * 64 + j * 16 + lr) * 32 + lg * 8;

  // K staging mapping: 64 rows x 64 u16; thread -> row tid>>2, col (tid&3)*16
  int krow = tid >> 2, kc16 = (tid & 3) * 16;
  u16x8 kreg0, kreg1;
  bf16x8 v[2][4];

  // prologue: cst -> LDS; K(0) -> Ks[0]; kreg = K(1); v = G(0)
  *reinterpret_cast<f32x4*>(&csm[tid * 4]) =
      *reinterpret_cast<const f32x4*>(cst + (size_t)z * S_ + tid * 4);
  kreg0 = *reinterpret_cast<const u16x8*>(K + (size_t)krow * D_ + kc16);
  kreg1 = *reinterpret_cast<const u16x8*>(K + (size_t)krow * D_ + kc16 + 8);
  *reinterpret_cast<u16x8*>(&Ks[0][krow][kc16]) = kreg0;
  *reinterpret_cast<u16x8*>(&Ks[0][krow][kc16 + 8]) = kreg1;
  kreg0 = *reinterpret_cast<const u16x8*>(K + (size_t)(64 + krow) * D_ + kc16);
  kreg1 = *reinterpret_cast<const u16x8*>(K + (size_t)(64 + krow) * D_ + kc16 + 8);
#pragma unroll
  for (int ks = 0; ks < 2; ks++)
#pragma unroll
    for (int j = 0; j < 4; j++)
      v[ks][j] = *reinterpret_cast<const bf16x8*>(Gb + (size_t)ks * 8192 + goff[j]);
  __syncthreads();

  f32x4 acc[4][4] = {};

#define WINDOW(IT, CUR)                                                           \
  do {                                                                            \
    int t0_ = (IT) * 64;                                                          \
    /* stage K(IT+1) -> Ks[CUR^1]; issue kreg = K(IT+2) */                        \
    *reinterpret_cast<u16x8*>(&Ks[(CUR) ^ 1][krow][kc16]) = kreg0;                \
    *reinterpret_cast<u16x8*>(&Ks[(CUR) ^ 1][krow][kc16 + 8]) = kreg1;            \
    {                                                                             \
      int tk_ = ((IT) + 2) & 15;                                                  \
      kreg0 = *reinterpret_cast<const u16x8*>(                                    \
          K + (size_t)(tk_ * 64 + krow) * D_ + kc16);                             \
      kreg1 = *reinterpret_cast<const u16x8*>(                                    \
          K + (size_t)(tk_ * 64 + krow) * D_ + kc16 + 8);                         \
    }                                                                             \
    /* QK(IT): 16 s x 64 t from Ks[CUR] */                                        \
    f32x4 sa_[4];                                                                 \
    _Pragma("unroll") for (int tf = 0; tf < 4; tf++) {                            \
      bf16x8 ka0_ = *reinterpret_cast<const bf16x8*>(                             \
          &Ks[CUR][tf * 16 + lr][lg * 8]);                                        \
      bf16x8 ka1_ = *reinterpret_cast<const bf16x8*>(                             \
          &Ks[CUR][tf * 16 + lr][32 + lg * 8]);                                   \
      f32x4 t_ = {};                                                              \
      t_ = MFMA16(ka0_, q[0], t_);                                                \
      sa_[tf] = MFMA16(ka1_, q[1], t_);                                           \
    }                                                                             \
    /* PV(IT-1): Ps[CUR^1] x v (G(IT-1)) -- independent, overlaps QK */           \
    if ((IT) > 0) {                                                               \
      __builtin_amdgcn_s_setprio(1);                                              \
      _Pragma("unroll") for (int ks = 0; ks < 2; ks++) {                          \
        bf16x8 ap_[4];                                                            \
        _Pragma("unroll") for (int i = 0; i < 4; i++)                             \
          ap_[i] = *reinterpret_cast<const bf16x8*>(                              \
              &Ps[(CUR) ^ 1][i * 16 + lr][ks * 32 + lg * 8]);                     \
        _Pragma("unroll") for (int i = 0; i < 4; i++)                             \
          _Pragma("unroll") for (int j = 0; j < 4; j++)                           \
            acc[i][j] = MFMA16(ap_[i], v[ks][j], acc[i][j]);                      \
      }                                                                           \
      __builtin_amdgcn_s_setprio(0);                                              \
      /* reload v = G(IT), consumed next window */                                \
      _Pragma("unroll") for (int ks = 0; ks < 2; ks++)                            \
        _Pragma("unroll") for (int j = 0; j < 4; j++)                             \
          v[ks][j] = *reinterpret_cast<const bf16x8*>(                            \
              Gb + ((size_t)(IT) * 2 + ks) * 8192 + goff[j]);                     \
    }                                                                             \
    /* exp2(QK) -> Ps[CUR]; c from LDS (broadcast) */                             \
    _Pragma("unroll") for (int tf = 0; tf < 4; tf++) {                            \
      f32x4 cv_ = *reinterpret_cast<const f32x4*>(&csm[t0_ + tf * 16 + lg * 4]);  \
      u16x4 p_;                                                                   \
      _Pragma("unroll") for (int r = 0; r < 4; r++)                               \
        p_[r] = f2bf_hw(EXP2(fmaf(sa_[tf][r], SCALE2, -cv_[r])));                 \
      *reinterpret_cast<u16x4*>(&Ps[CUR][w * 16 + lr][tf * 16 + lg * 4]) = p_;    \
    }                                                                             \
    __syncthreads();                                                              \
  } while (0)

  for (int it2 = 0; it2 < 8; ++it2) {
    WINDOW(it2 * 2, 0);
    WINDOW(it2 * 2 + 1, 1);
  }
#undef WINDOW

  { // final PV(15): Ps[1] x v = G(15)
#pragma unroll
    for (int ks = 0; ks < 2; ks++) {
      bf16x8 ap_[4];
#pragma unroll
      for (int i = 0; i < 4; i++)
        ap_[i] = *reinterpret_cast<const bf16x8*>(&Ps[1][i * 16 + lr][ks * 32 + lg * 8]);
#pragma unroll
      for (int i = 0; i < 4; i++)
#pragma unroll
        for (int j = 0; j < 4; j++)
          acc[i][j] = MFMA16(ap_[i], v[ks][j], acc[i][j]);
    }
  }

  // epilogue: out[b][h*S + s][e] = acc + bo[e]
  float bov[4];
#pragma unroll
  for (int j = 0; j < 4; j++) bov[j] = bo[eblk * 256 + w * 64 + j * 16 + lr];
#pragma unroll
  for (int i = 0; i < 4; i++)
#pragma unroll
    for (int j = 0; j < 4; j++)
#pragma unroll
      for (int r = 0; r < 4; r++) {
        int s = sblk * 64 + i * 16 + lg * 4 + r;
        int col = eblk * 256 + w * 64 + j * 16 + lr;
        out[((size_t)b * (H_ * S_) + (size_t)h * S_ + s) * E_ + col] =
            acc[i][j][r] + bov[j];
      }
}

extern "C" void kernel_launch(void* const* d_in, const int* in_sizes, int n_in,
                              void* d_out, int out_size, void* d_ws, size_t ws_size,
                              hipStream_t stream) {
  const float* h  = (const float*)d_in[0];
  const float* Wq = (const float*)d_in[1];
  const float* bq = (const float*)d_in[2];
  const float* Wk = (const float*)d_in[3];
  const float* bk = (const float*)d_in[4];
  // d_in[5] = Wv, d_in[6] = bv: dead weights in the reference
  const float* Wo = (const float*)d_in[7];
  const float* bo = (const float*)d_in[8];
  float* out = (float*)d_out;

  char* p = (char*)d_ws;
  unsigned short* hb  = (unsigned short*)p; p += (size_t)B_ * S_ * E_ * 2;
  unsigned short* WoT = (unsigned short*)p; p += (size_t)E_ * E_ * 2;
  unsigned short* WqT = (unsigned short*)p; p += (size_t)H_ * D_ * E_ * 2;
  unsigned short* WkT = (unsigned short*)p; p += (size_t)H_ * D_ * E_ * 2;
  unsigned short* Qb  = (unsigned short*)p; p += (size_t)B_ * H_ * S_ * D_ * 2;
  unsigned short* Kb  = (unsigned short*)p; p += (size_t)B_ * H_ * S_ * D_ * 2;
  unsigned short* Gt  = (unsigned short*)p; p += (size_t)B_ * E_ * S_ * 2;
  float*          cst = (float*)p;          p += (size_t)B_ * H_ * S_ * 4;

  int n4 = B_ * S_ * E_ / 4;
  cast_f32_bf16_kernel<<<dim3(n4 / 256), 256, 0, stream>>>(h, hb, n4);
  transpose_cast_kernel<<<dim3(16, 16, 1), 256, 0, stream>>>(Wo, WoT, E_, E_);
  transpose_cast_kernel<<<dim3(1, 16, H_), 256, 0, stream>>>(Wq, WqT, E_, D_);
  transpose_cast_kernel<<<dim3(1, 16, H_), 256, 0, stream>>>(Wk, WkT, E_, D_);
  gemm_G_kernel<<<dim3(8, 8, B_), 256, 0, stream>>>(hb, WoT, Gt);
  proj_qk_kernel<<<dim3(8, B_ * H_), 256, 0, stream>>>(hb, WqT, WkT, bq, bk, Qb, Kb);
  stats_kernel<<<dim3(S_ / 256, B_ * H_), 256, 0, stream>>>(Qb, Kb, cst);
  attn_kernel<<<dim3(8192), 256, 0, stream>>>(Qb, Kb, Gt, cst, bo, out);
}